// Round 2
// baseline (57.155 us; speedup 1.0000x reference)
//
#include <hip/hip_runtime.h>

// Problem constants (from reference: x [16, 32, 64, 32, 32] f32)
constexpr int T_DIM   = 16;
constexpr int B_DIM   = 32;
constexpr int FEAT    = 64 * 32 * 32;   // 65536 features per (t,b)
constexpr int THREADS = 256;
constexpr int NCHUNK  = 32;             // blocks per b -> 1024 blocks = 4/CU exactly
constexpr int FPB     = FEAT / NCHUNK;  // 2048 features per block
constexpr int ITERS   = FPB / (THREADS * 4); // 2 float4 groups per thread

// Folded multi-value butterfly stage: fold 2*HALF values into HALF values,
// splitting across lane pairs (mask M). All indices compile-time (registers).
#define FOLD_STAGE(M, HALF)                                            \
    {                                                                  \
        const bool up = (lane & (M)) != 0;                             \
        _Pragma("unroll") for (int i = 0; i < (HALF); ++i) {           \
            float send = up ? val[i] : val[i + (HALF)];                \
            float recv = __shfl_xor(send, (M), 64);                    \
            val[i] = (up ? val[i + (HALF)] : val[i]) + recv;           \
        }                                                              \
    }

// Pass 1: one read of x. Each thread owns float4 feature groups; keeps the
// 16 relu-cumsums in registers; per iteration computes 32 per-t scalars
// (sum r^2, sum s[t]*s[15]) and folds them across the wave immediately,
// accumulating ONE register per lane. __launch_bounds__(256,4) caps VGPR
// at 128 so all 1024 blocks are co-resident (16 waves/CU) -> no tail round.
__global__ __launch_bounds__(THREADS, 4) void snn_pass1(
    const float* __restrict__ x, float* __restrict__ partial) {
    const int b     = blockIdx.x;   // 0..31
    const int chunk = blockIdx.y;   // 0..31
    const int tid   = threadIdx.x;
    const int lane  = tid & 63;
    const int wave  = tid >> 6;

    const size_t base_b   = (size_t)b * FEAT;
    const size_t tstride4 = (size_t)B_DIM * FEAT / 4;  // t-stride in float4 units

    float acc = 0.f;  // folded: this lane's share of one of the 32 values

    for (int it = 0; it < ITERS; ++it) {
        const int f = chunk * FPB + (it * THREADS + tid) * 4;
        const float4* p = reinterpret_cast<const float4*>(x + base_b + f);

        float4 s[T_DIM];
        float4 run = make_float4(0.f, 0.f, 0.f, 0.f);
#pragma unroll
        for (int t = 0; t < T_DIM; ++t) {
            float4 v = p[(size_t)t * tstride4];
            run.x += fmaxf(v.x, 0.f);
            run.y += fmaxf(v.y, 0.f);
            run.z += fmaxf(v.z, 0.f);
            run.w += fmaxf(v.w, 0.f);
            s[t] = run;
        }
        const float4 sf = run;  // s[15]

        float val[32];  // val[t] = A-contrib, val[16+t] = B-contrib
#pragma unroll
        for (int t = 0; t < T_DIM; ++t) {
            const float invt = 1.f / (float)(t + 1);
            const float4 st  = s[t];
            val[t] = (st.x * st.x + st.y * st.y + st.z * st.z + st.w * st.w)
                     * (invt * invt);
            val[16 + t] = (st.x * sf.x + st.y * sf.y + st.z * sf.z + st.w * sf.w)
                          * (invt * (1.f / 16.f));
        }

        // Fold 32 values across 32-lane groups: 16+8+4+2+1 = 31 shuffles.
        FOLD_STAGE(1, 16)
        FOLD_STAGE(2, 8)
        FOLD_STAGE(4, 4)
        FOLD_STAGE(8, 2)
        FOLD_STAGE(16, 1)
        // Combine the two 32-lane halves: full 64-lane sum.
        acc += val[0] + __shfl_xor(val[0], 32, 64);
    }

    // Lane -> value-index mapping from the fold order (bit-reversed halves).
    const int l = lane & 31;
    const int vidx = ((l & 1) << 4) | ((l & 2) << 2) | (l & 4) |
                     ((l & 8) >> 2) | ((l & 16) >> 4);

    __shared__ float red[4][32];
    if (lane < 32) red[wave][vidx] = acc;   // vidx is a permutation: conflict-free
    __syncthreads();
    if (tid < 32) {
        float s4 = red[0][tid] + red[1][tid] + red[2][tid] + red[3][tid];
        partial[((size_t)b * NCHUNK + chunk) * 32 + tid] = s4;
    }
}

// Pass 2: reduce chunks, finalize per-b scalar.
__global__ __launch_bounds__(64) void snn_finalize(
    const float* __restrict__ partial, float* __restrict__ out) {
    const int b   = blockIdx.x;   // 0..31
    const int tid = threadIdx.x;  // 64 threads = 1 wave
    const int v   = tid & 31;     // value index 0..31
    const int h   = tid >> 5;     // chunk half

    float acc = 0.f;
#pragma unroll
    for (int i = 0; i < NCHUNK / 2; ++i) {
        const int c = h * (NCHUNK / 2) + i;
        acc += partial[((size_t)b * NCHUNK + c) * 32 + v];
    }
    acc += __shfl_xor(acc, 32, 64);  // lanes 0..31 now hold full sums

    __shared__ float sA[16];
    __shared__ float sB[16];
    if (tid < 16)                    sA[tid] = acc;
    else if (tid < 32)               sB[tid - 16] = acc;
    __syncthreads();

    if (tid == 0) {
        const float n15 = sqrtf(sA[15] + 1e-5f);
        float csum = 0.f;
#pragma unroll
        for (int t = 0; t < 16; ++t) {
            const float nt = sqrtf(sA[t] + 1e-5f);
            csum += sB[t] / (nt * n15);
        }
        const float cs = csum * (1.f / 16.f);
        out[b] = 1.f / (cs + 1e-5f);
    }
}

extern "C" void kernel_launch(void* const* d_in, const int* in_sizes, int n_in,
                              void* d_out, int out_size, void* d_ws, size_t ws_size,
                              hipStream_t stream) {
    const float* x   = (const float*)d_in[0];  // [16, 32, 64, 32, 32]
    float* out       = (float*)d_out;          // [1, 32]
    float* partial   = (float*)d_ws;           // 32 * 32 * 32 floats = 128 KB

    dim3 grid1(B_DIM, NCHUNK);
    snn_pass1<<<grid1, THREADS, 0, stream>>>(x, partial);
    snn_finalize<<<B_DIM, 64, 0, stream>>>(partial, out);
}